// Round 5
// baseline (5445.102 us; speedup 1.0000x reference)
//
#include <hip/hip_runtime.h>

#define B_ 8
#define S_ 1024
#define H_ 1024
#define NH_ 4
#define D_ 256

typedef unsigned int u32;
typedef unsigned short u16;

// ---------------- mask dtype detection ----------------
// fl[1] = OR of first 64K words of mask; fl[2] = code: 0=u8, 1=int32, 2=bf16, 3=fp32
__global__ void init_flags_k(int* fl) { fl[0] = 0; fl[1] = 0; fl[2] = 0; }

__global__ __launch_bounds__(256) void or_mask_k(const u32* __restrict__ m, int* __restrict__ fl) {
    u32 v = m[blockIdx.x * 256 + threadIdx.x];   // first 256 KiB: in range for every encoding
#pragma unroll
    for (int o = 32; o; o >>= 1) v |= __shfl_xor(v, o, 64);
    if ((threadIdx.x & 63) == 0) atomicOr(fl + 1, (int)v);
}

__global__ void classify_mask_k(int* fl) {
    u32 R = (u32)fl[1];
    int c;
    if (R == 0x3F803F80u)      c = 2;  // bf16 {0,1.0} pairs
    else if (R == 0x3F800000u) c = 3;  // fp32 {0,1.0}
    else if (R & 0xFFFFFF00u)  c = 0;  // u8 bool
    else                       c = 1;  // int32 0/1
    fl[2] = c;
}

// ---------------- per-b GEMM: C[1024,1024] = A[1024,1024] @ W[1024,1024]  (all fp32) ----------------
__global__ __launch_bounds__(256) void gemm_qkv_k(const float* __restrict__ A, const float* __restrict__ W,
                                                  float* __restrict__ C) {
    __shared__ float As[16][64];   // [k][m]
    __shared__ float Bs[16][64];   // [k][n]
    const int t = threadIdx.x;
    const int n0 = blockIdx.x * 64, m0 = blockIdx.y * 64;
    const int tx = t & 15, ty = t >> 4;
    float acc[4][4] = {};
    for (int k0 = 0; k0 < 1024; k0 += 16) {
        __syncthreads();
#pragma unroll
        for (int i = 0; i < 2; i++) {
            int e = t + i * 256;               // [0,512)
            int r = e >> 3, c2 = e & 7;        // r<64 (m), c2<8 (k-pair)
            float2 v = *(const float2*)(A + (size_t)(m0 + r) * H_ + k0 + c2 * 2);
            As[c2 * 2][r] = v.x; As[c2 * 2 + 1][r] = v.y;
        }
#pragma unroll
        for (int i = 0; i < 2; i++) {
            int e = t + i * 256;
            int r = e >> 5, c2 = e & 31;       // r<16 (k), c2<32 (n-pair)
            float2 v = *(const float2*)(W + (size_t)(k0 + r) * H_ + n0 + c2 * 2);
            Bs[r][c2 * 2] = v.x; Bs[r][c2 * 2 + 1] = v.y;
        }
        __syncthreads();
#pragma unroll
        for (int kk = 0; kk < 16; kk++) {
            float4 a4 = *(const float4*)&As[kk][ty * 4];
            float4 b4 = *(const float4*)&Bs[kk][tx * 4];
            float av[4] = {a4.x, a4.y, a4.z, a4.w};
            float bv[4] = {b4.x, b4.y, b4.z, b4.w};
#pragma unroll
            for (int mi = 0; mi < 4; mi++)
#pragma unroll
                for (int ni = 0; ni < 4; ni++)
                    acc[mi][ni] = fmaf(av[mi], bv[ni], acc[mi][ni]);
        }
    }
#pragma unroll
    for (int mi = 0; mi < 4; mi++) {
        *(float4*)(C + (size_t)(m0 + ty * 4 + mi) * H_ + n0 + tx * 4) =
            make_float4(acc[mi][0], acc[mi][1], acc[mi][2], acc[mi][3]);
    }
}

// ---------------- per-b fused scores + gauss + mask + softmax + query_mask -> attn (fp32) ----------------
__global__ __launch_bounds__(256) void attn_k(const float* __restrict__ Q, const float* __restrict__ Km,
                                              const void* __restrict__ mask,
                                              const float* __restrict__ qmask, const float* __restrict__ gfac,
                                              const int* __restrict__ fl, float* __restrict__ attn, int b) {
    __shared__ float Qs[4][256];
    __shared__ float Ks[32][257];
    __shared__ float Sc[4][1024];
    const int t = threadIdx.x;
    const int q0 = blockIdx.x * 4, h = blockIdx.z;
    const float g = gfac[0];
    const int code = fl[2];
    {   // stage 4 Q rows (4 x 256 fp32)
        int r = t >> 6, c4 = t & 63;
        float4 v = *(const float4*)(Q + (size_t)(q0 + r) * H_ + h * D_ + c4 * 4);
        Qs[r][c4 * 4 + 0] = v.x; Qs[r][c4 * 4 + 1] = v.y;
        Qs[r][c4 * 4 + 2] = v.z; Qs[r][c4 * 4 + 3] = v.w;
    }
    const int half = t & 1, kl = (t >> 1) & 31, q = t >> 6;
    const int qg = q0 + q;
    const int d0 = half * 128;
    for (int kc = 0; kc < 32; kc++) {
        __syncthreads();
#pragma unroll
        for (int i = 0; i < 8; i++) {
            int e = t + i * 256;               // [0,2048)
            int r = e >> 6, c4 = e & 63;       // r<32, c4<64
            float4 v = *(const float4*)(Km + (size_t)(kc * 32 + r) * H_ + h * D_ + c4 * 4);
            Ks[r][c4 * 4 + 0] = v.x; Ks[r][c4 * 4 + 1] = v.y;
            Ks[r][c4 * 4 + 2] = v.z; Ks[r][c4 * 4 + 3] = v.w;
        }
        __syncthreads();
        float s = 0.f;
#pragma unroll
        for (int d = 0; d < 128; d += 4) {
            float4 qv = *(const float4*)&Qs[q][d0 + d];
            s = fmaf(qv.x, Ks[kl][d0 + d],     s);
            s = fmaf(qv.y, Ks[kl][d0 + d + 1], s);
            s = fmaf(qv.z, Ks[kl][d0 + d + 2], s);
            s = fmaf(qv.w, Ks[kl][d0 + d + 3], s);
        }
        s += __shfl_xor(s, 1, 64);             // combine the two 128-d halves
        if (half == 0) {
            int kg = kc * 32 + kl;
            float diff = (float)(qg - kg);
            float val = s * 0.0625f - diff * diff / g;
            size_t midx = ((size_t)b * S_ + qg) * S_ + kg;
            int mv;
            if (code == 0)      mv = ((const unsigned char*)mask)[midx];
            else if (code == 1) mv = ((const int*)mask)[midx];
            else if (code == 2) mv = (((const u16*)mask)[midx] != 0);
            else                mv = (((const u32*)mask)[midx] != 0);
            if (mv) val = -4294967296.0f;      // fp32(-2^32+1)
            Sc[q][kg] = val;
        }
    }
    __syncthreads();
    // softmax: one wave per q-row
    const int j = t & 63;
    float mx = -3.4e38f;
    for (int k = j; k < S_; k += 64) mx = fmaxf(mx, Sc[q][k]);
#pragma unroll
    for (int o = 32; o; o >>= 1) mx = fmaxf(mx, __shfl_xor(mx, o, 64));
    float sum = 0.f;
    for (int k = j; k < S_; k += 64) {
        float e = __expf(Sc[q][k] - mx);
        Sc[q][k] = e;
        sum += e;
    }
#pragma unroll
    for (int o = 32; o; o >>= 1) sum += __shfl_xor(sum, o, 64);
    float qmv = qmask[b * S_ + qg];
    float inv = qmv / sum;
    float* orow = attn + ((size_t)(h * B_ + b) * S_ + qg) * S_;
    for (int k = j; k < S_; k += 64) orow[k] = Sc[q][k] * inv;
}

// ---------------- per-b res = attn @ V  (fp32) ----------------
__global__ __launch_bounds__(256) void pv_k(const float* __restrict__ attn, const float* __restrict__ V,
                                            float* __restrict__ res, int b) {
    __shared__ float Ps[8][33];     // 8 q-rows x 32 k, +1 pad
    __shared__ float Vs[32][260];   // 32 k-rows x 256 d, +4 pad
    const int t = threadIdx.x;
    const int q0 = blockIdx.x * 8, h = blockIdx.z;
    const int q = t >> 5, j = t & 31;
    float acc[8] = {};
    for (int kc = 0; kc < 32; kc++) {
        __syncthreads();
        {
            int r = t >> 5, c = t & 31;
            Ps[r][c] = attn[((size_t)(h * B_ + b) * S_ + q0 + r) * S_ + kc * 32 + c];
        }
#pragma unroll
        for (int i = 0; i < 8; i++) {
            int e = t + i * 256;
            int r = e >> 6, c4 = e & 63;
            float4 v = *(const float4*)(V + (size_t)(kc * 32 + r) * H_ + h * D_ + c4 * 4);
            Vs[r][c4 * 4 + 0] = v.x; Vs[r][c4 * 4 + 1] = v.y;
            Vs[r][c4 * 4 + 2] = v.z; Vs[r][c4 * 4 + 3] = v.w;
        }
        __syncthreads();
#pragma unroll
        for (int k = 0; k < 32; k++) {
            float p = Ps[q][k];
#pragma unroll
            for (int c = 0; c < 8; c++)
                acc[c] = fmaf(p, Vs[k][j * 8 + c], acc[c]);
        }
    }
    *(float4*)(res + (size_t)(q0 + q) * H_ + h * D_ + j * 8)     = make_float4(acc[0], acc[1], acc[2], acc[3]);
    *(float4*)(res + (size_t)(q0 + q) * H_ + h * D_ + j * 8 + 4) = make_float4(acc[4], acc[5], acc[6], acc[7]);
}

// ---------------- per-b tmp = [dec_b,res_b] @ Wf + bf + dec_b (fp32) ----------------
__global__ __launch_bounds__(256) void gemm_final_k(const float* __restrict__ dec, const float* __restrict__ res,
                                                    const float* __restrict__ Wf, const float* __restrict__ bfv,
                                                    float* __restrict__ tmp) {
    __shared__ float As[16][64];
    __shared__ float Bs[16][64];
    const int t = threadIdx.x;
    const int n0 = blockIdx.x * 64, m0 = blockIdx.y * 64;
    const int tx = t & 15, ty = t >> 4;
    float acc[4][4] = {};
    for (int k0 = 0; k0 < 2048; k0 += 16) {
        const float* Ap = (k0 < 1024) ? (dec + k0) : (res + (k0 - 1024));
        __syncthreads();
#pragma unroll
        for (int i = 0; i < 2; i++) {
            int e = t + i * 256;
            int r = e >> 3, c2 = e & 7;
            float2 v = *(const float2*)(Ap + (size_t)(m0 + r) * H_ + c2 * 2);
            As[c2 * 2][r] = v.x; As[c2 * 2 + 1][r] = v.y;
        }
#pragma unroll
        for (int i = 0; i < 2; i++) {
            int e = t + i * 256;
            int r = e >> 5, c2 = e & 31;
            float2 v = *(const float2*)(Wf + (size_t)(k0 + r) * H_ + n0 + c2 * 2);
            Bs[r][c2 * 2] = v.x; Bs[r][c2 * 2 + 1] = v.y;
        }
        __syncthreads();
#pragma unroll
        for (int kk = 0; kk < 16; kk++) {
            float4 a4 = *(const float4*)&As[kk][ty * 4];
            float4 b4 = *(const float4*)&Bs[kk][tx * 4];
            float av[4] = {a4.x, a4.y, a4.z, a4.w};
            float bv[4] = {b4.x, b4.y, b4.z, b4.w};
#pragma unroll
            for (int mi = 0; mi < 4; mi++)
#pragma unroll
                for (int ni = 0; ni < 4; ni++)
                    acc[mi][ni] = fmaf(av[mi], bv[ni], acc[mi][ni]);
        }
    }
#pragma unroll
    for (int mi = 0; mi < 4; mi++) {
        const int m = m0 + ty * 4 + mi;
        float ov[4];
#pragma unroll
        for (int ni = 0; ni < 4; ni++) {
            int n = n0 + tx * 4 + ni;
            ov[ni] = acc[mi][ni] + bfv[n] + dec[(size_t)m * H_ + n];
        }
        *(float4*)(tmp + (size_t)m * H_ + n0 + tx * 4) = make_float4(ov[0], ov[1], ov[2], ov[3]);
    }
}

// ---------------- per-b LayerNorm -> fp32 out ----------------
__global__ __launch_bounds__(256) void ln_k(const float* __restrict__ tmp, const float* __restrict__ gm,
                                            const float* __restrict__ bt, float* __restrict__ out) {
    const int m = blockIdx.x, t = threadIdx.x;
    float4 x = ((const float4*)(tmp + (size_t)m * H_))[t];
    float xa[4] = {x.x, x.y, x.z, x.w};
    float s = 0.f, s2 = 0.f;
#pragma unroll
    for (int i = 0; i < 4; i++) { s += xa[i]; s2 += xa[i] * xa[i]; }
#pragma unroll
    for (int o = 32; o; o >>= 1) { s += __shfl_xor(s, o, 64); s2 += __shfl_xor(s2, o, 64); }
    __shared__ float rs[4], rs2[4];
    if ((t & 63) == 0) { rs[t >> 6] = s; rs2[t >> 6] = s2; }
    __syncthreads();
    s  = rs[0] + rs[1] + rs[2] + rs[3];
    s2 = rs2[0] + rs2[1] + rs2[2] + rs2[3];
    float mu = s * (1.f / 1024.f);
    float var = s2 * (1.f / 1024.f) - mu * mu;
    float rstd = rsqrtf(var + 1e-5f);
    float ov[4];
#pragma unroll
    for (int i = 0; i < 4; i++) {
        int n = t * 4 + i;
        ov[i] = (xa[i] - mu) * rstd * gm[n] + bt[n];
    }
    *(float4*)(out + (size_t)m * H_ + t * 4) = make_float4(ov[0], ov[1], ov[2], ov[3]);
}

extern "C" void kernel_launch(void* const* d_in, const int* in_sizes, int n_in,
                              void* d_out, int out_size, void* d_ws, size_t ws_size,
                              hipStream_t stream) {
    const float* memory = (const float*)d_in[0];
    const float* dec    = (const float*)d_in[1];
    const void*  mask   = d_in[2];
    const float* qmask  = (const float*)d_in[3];
    const float* Wk     = (const float*)d_in[4];
    const float* Wv     = (const float*)d_in[5];
    const float* Wq     = (const float*)d_in[6];
    const float* Wf     = (const float*)d_in[7];
    const float* bfv    = (const float*)d_in[8];
    const float* gamma  = (const float*)d_in[9];
    const float* beta   = (const float*)d_in[10];
    const float* gfac   = (const float*)d_in[11];

    // ---- per-batch fp32 workspace: 21 MiB peak ----
    // [0,1M): flags  [1M,5M): Qb  [5M,9M): Kb  [9M,13M): Vb  [13M,17M): Rb  [17M,21M): tmp
    char* ws = (char*)d_ws;
    int*   fl  = (int*)ws;
    float* Qb  = (float*)(ws + (1u  << 20));
    float* Kb  = (float*)(ws + (5u  << 20));
    float* Vb  = (float*)(ws + (9u  << 20));
    float* Rb  = (float*)(ws + (13u << 20));
    float* tmp = (float*)(ws + (17u << 20));

    float* out  = (float*)d_out;                      // fp32! (reference output dtype)
    float* attn = out + (size_t)B_ * S_ * H_;         // fp32 attn (NH*B, S, S)

    init_flags_k<<<1, 1, 0, stream>>>(fl);
    or_mask_k<<<256, 256, 0, stream>>>((const u32*)mask, fl);
    classify_mask_k<<<1, 1, 0, stream>>>(fl);

    dim3 gg(16, 16);   // (N/64, M/64) for M=1024
    for (int b = 0; b < B_; b++) {
        const float* mem_b = memory + (size_t)b * S_ * H_;
        const float* dec_b = dec    + (size_t)b * S_ * H_;
        gemm_qkv_k<<<gg, 256, 0, stream>>>(dec_b, Wq, Qb);
        gemm_qkv_k<<<gg, 256, 0, stream>>>(mem_b, Wk, Kb);
        gemm_qkv_k<<<gg, 256, 0, stream>>>(mem_b, Wv, Vb);
        attn_k<<<dim3(256, 1, 4), 256, 0, stream>>>(Qb, Kb, mask, qmask, gfac, fl, attn, b);
        pv_k<<<dim3(128, 1, 4), 256, 0, stream>>>(attn, Vb, Rb, b);
        gemm_final_k<<<gg, 256, 0, stream>>>(dec_b, Rb, Wf, bfv, tmp);
        ln_k<<<1024, 256, 0, stream>>>(tmp, gamma, beta, out + (size_t)b * S_ * H_);
    }
}

// Round 6
// 696.117 us; speedup vs baseline: 7.8221x; 7.8221x over previous
//
#include <hip/hip_runtime.h>

#define B_ 8
#define S_ 1024
#define H_ 1024
#define NH_ 4
#define D_ 256
#define M_ 8192

typedef unsigned int u32;
typedef unsigned short u16;
typedef __attribute__((ext_vector_type(4))) float f32x4;
typedef __attribute__((ext_vector_type(8))) short s16x8;

__device__ __forceinline__ float bf2f(u16 b) { return __uint_as_float(((u32)b) << 16); }
__device__ __forceinline__ u16 f2bf(float f) {
    u32 x = __float_as_uint(f);
    return (u16)((x + 0x7fffu + ((x >> 16) & 1u)) >> 16);   // RNE
}

// ---------------- mask dtype detection ----------------
__global__ void init_flags_k(int* fl) { fl[0] = 0; fl[1] = 0; fl[2] = 0; }

__global__ __launch_bounds__(256) void or_mask_k(const u32* __restrict__ m, int* __restrict__ fl) {
    u32 v = m[blockIdx.x * 256 + threadIdx.x];   // first 256 KiB: in range for every encoding
#pragma unroll
    for (int o = 32; o; o >>= 1) v |= __shfl_xor(v, o, 64);
    if ((threadIdx.x & 63) == 0) atomicOr(fl + 1, (int)v);
}

__global__ void classify_mask_k(int* fl) {
    u32 R = (u32)fl[1];
    int c;
    if (R == 0x3F803F80u)      c = 2;  // bf16 {0,1}
    else if (R == 0x3F800000u) c = 3;  // fp32 {0,1}
    else if (R & 0xFFFFFF00u)  c = 0;  // u8 bool
    else                       c = 1;  // int32
    fl[2] = c;
}

// ---------------- transpose-cast: dst[c][r] (bf16) = src[r][c] (fp32) ----------------
__global__ __launch_bounds__(256) void tcast_k(const float* __restrict__ src, u16* __restrict__ dst,
                                               int R, int C) {
    __shared__ float sb[32][33];
    const int c0 = blockIdx.x * 32, r0 = blockIdx.y * 32;
    const int tx = threadIdx.x & 31, ty = threadIdx.x >> 5;   // ty in [0,8)
#pragma unroll
    for (int i = 0; i < 4; i++)
        sb[ty + 8 * i][tx] = src[(size_t)(r0 + ty + 8 * i) * C + c0 + tx];
    __syncthreads();
#pragma unroll
    for (int i = 0; i < 4; i++)
        dst[(size_t)(c0 + ty + 8 * i) * R + r0 + tx] = f2bf(sb[tx][ty + 8 * i]);
}

// ---------------- MFMA GEMM core: C(128x128 tile) = A[m][k] * B[n][k]^T ----------------
// AMODE: 0 = A fp32, 1 = A bf16, 2 = concat (k<1024: fp32 A32; k>=1024: bf16 A16)
template<int AMODE>
__device__ __forceinline__ void gemm_core(
    const float* __restrict__ A32, const u16* __restrict__ A16, int lda,
    const u16* __restrict__ Bp, int ldb, int K, int m0, int n0,
    short* As, short* Bs, f32x4 acc[4][4])
{
    const int t = threadIdx.x;
    const int lane = t & 63, wave = t >> 6;
    const int wy = wave >> 1, wx = wave & 1;
    const int mq = lane >> 4, ml = lane & 15;
    const int srow = t >> 2, skq = t & 3;

    for (int k0 = 0; k0 < K; k0 += 32) {
        __syncthreads();
        // stage A-tile: 128 rows x 32 k (bf16, row stride 40)
#pragma unroll
        for (int it = 0; it < 2; it++) {
            const int row = srow + it * 64;
            const int kk = k0 + skq * 8;
            short* dst = As + row * 40 + skq * 8;
            if (AMODE == 0) {
                const float* s = A32 + (size_t)(m0 + row) * lda + kk;
                float4 v0 = *(const float4*)s, v1 = *(const float4*)(s + 4);
                s16x8 p;
                p[0] = (short)f2bf(v0.x); p[1] = (short)f2bf(v0.y);
                p[2] = (short)f2bf(v0.z); p[3] = (short)f2bf(v0.w);
                p[4] = (short)f2bf(v1.x); p[5] = (short)f2bf(v1.y);
                p[6] = (short)f2bf(v1.z); p[7] = (short)f2bf(v1.w);
                *(s16x8*)dst = p;
            } else if (AMODE == 1) {
                *(s16x8*)dst = *(const s16x8*)(A16 + (size_t)(m0 + row) * lda + kk);
            } else {
                if (kk < 1024) {
                    const float* s = A32 + (size_t)(m0 + row) * 1024 + kk;
                    float4 v0 = *(const float4*)s, v1 = *(const float4*)(s + 4);
                    s16x8 p;
                    p[0] = (short)f2bf(v0.x); p[1] = (short)f2bf(v0.y);
                    p[2] = (short)f2bf(v0.z); p[3] = (short)f2bf(v0.w);
                    p[4] = (short)f2bf(v1.x); p[5] = (short)f2bf(v1.y);
                    p[6] = (short)f2bf(v1.z); p[7] = (short)f2bf(v1.w);
                    *(s16x8*)dst = p;
                } else {
                    *(s16x8*)dst = *(const s16x8*)(A16 + (size_t)(m0 + row) * 1024 + (kk - 1024));
                }
            }
        }
        // stage B-tile: 128 rows (n) x 32 k (bf16)
#pragma unroll
        for (int it = 0; it < 2; it++) {
            const int row = srow + it * 64;
            *(s16x8*)(Bs + row * 40 + skq * 8) =
                *(const s16x8*)(Bp + (size_t)(n0 + row) * ldb + k0 + skq * 8);
        }
        __syncthreads();
        s16x8 af[4], bfr[4];
#pragma unroll
        for (int i = 0; i < 4; i++) {
            af[i]  = *(s16x8*)(As + (wy * 64 + i * 16 + ml) * 40 + mq * 8);
            bfr[i] = *(s16x8*)(Bs + (wx * 64 + i * 16 + ml) * 40 + mq * 8);
        }
#pragma unroll
        for (int mi = 0; mi < 4; mi++)
#pragma unroll
            for (int ni = 0; ni < 4; ni++)
                acc[mi][ni] = __builtin_amdgcn_mfma_f32_16x16x32_bf16(af[mi], bfr[ni], acc[mi][ni], 0, 0, 0);
    }
}

// ---------------- QKV projection: C[m][n] bf16 = A(fp32) @ WT(bf16)^T ----------------
__global__ __launch_bounds__(256) void gemm_proj_k(const float* __restrict__ A, const u16* __restrict__ WT,
                                                   u16* __restrict__ C) {
    __shared__ short As[128 * 40];
    __shared__ short Bs[128 * 40];
    const int m0 = blockIdx.y * 128, n0 = blockIdx.x * 128;
    f32x4 acc[4][4];
#pragma unroll
    for (int i = 0; i < 4; i++)
#pragma unroll
        for (int j = 0; j < 4; j++) acc[i][j] = 0;
    gemm_core<0>(A, nullptr, H_, WT, H_, H_, m0, n0, As, Bs, acc);
    const int lane = threadIdx.x & 63, wave = threadIdx.x >> 6;
    const int wy = wave >> 1, wx = wave & 1, mq = lane >> 4, ml = lane & 15;
#pragma unroll
    for (int mi = 0; mi < 4; mi++)
#pragma unroll
        for (int ni = 0; ni < 4; ni++) {
            const int n = n0 + wx * 64 + ni * 16 + ml;
#pragma unroll
            for (int r = 0; r < 4; r++) {
                const int m = m0 + wy * 64 + mi * 16 + mq * 4 + r;
                C[(size_t)m * H_ + n] = f2bf(acc[mi][ni][r]);
            }
        }
}

// ---------------- V projection with transposed store: VT[b*1024 + n][s] ----------------
__global__ __launch_bounds__(256) void gemm_vt_k(const float* __restrict__ A, const u16* __restrict__ WT,
                                                 u16* __restrict__ VT) {
    __shared__ short As[128 * 40];
    __shared__ short Bs[128 * 40];
    const int m0 = blockIdx.y * 128, n0 = blockIdx.x * 128;
    f32x4 acc[4][4];
#pragma unroll
    for (int i = 0; i < 4; i++)
#pragma unroll
        for (int j = 0; j < 4; j++) acc[i][j] = 0;
    gemm_core<0>(A, nullptr, H_, WT, H_, H_, m0, n0, As, Bs, acc);
    const int lane = threadIdx.x & 63, wave = threadIdx.x >> 6;
    const int wy = wave >> 1, wx = wave & 1, mq = lane >> 4, ml = lane & 15;
#pragma unroll
    for (int mi = 0; mi < 4; mi++)
#pragma unroll
        for (int ni = 0; ni < 4; ni++) {
            const int n = n0 + wx * 64 + ni * 16 + ml;
            const int mbase = m0 + wy * 64 + mi * 16 + mq * 4;   // 4-aligned, same b for all 4
            const int b = mbase >> 10, s = mbase & 1023;
            ushort4 w;
            w.x = f2bf(acc[mi][ni][0]); w.y = f2bf(acc[mi][ni][1]);
            w.z = f2bf(acc[mi][ni][2]); w.w = f2bf(acc[mi][ni][3]);
            *(ushort4*)(VT + ((size_t)(b * 1024 + n)) * 1024 + s) = w;
        }
}

// ---------------- QK^T + gauss + mask -> logits fp32 (into d_out attn region) ----------------
__global__ __launch_bounds__(256) void qk_logits_k(const u16* __restrict__ Qb, const u16* __restrict__ Kb,
                                                   const void* __restrict__ mask,
                                                   const float* __restrict__ gfac, const int* __restrict__ fl,
                                                   float* __restrict__ logits) {
    __shared__ short As[128 * 40];
    __shared__ short Bs[128 * 40];
    const int z = blockIdx.z, h = z >> 3, b = z & 7;
    const u16* Aq = Qb + (size_t)b * S_ * H_ + h * D_;
    const u16* Bk = Kb + (size_t)b * S_ * H_ + h * D_;
    const int m0 = blockIdx.y * 128, n0 = blockIdx.x * 128;
    f32x4 acc[4][4];
#pragma unroll
    for (int i = 0; i < 4; i++)
#pragma unroll
        for (int j = 0; j < 4; j++) acc[i][j] = 0;
    gemm_core<1>(nullptr, Aq, H_, Bk, H_, D_, m0, n0, As, Bs, acc);
    const float g = gfac[0];
    const int code = fl[2];
    const int lane = threadIdx.x & 63, wave = threadIdx.x >> 6;
    const int wy = wave >> 1, wx = wave & 1, mq = lane >> 4, ml = lane & 15;
#pragma unroll
    for (int mi = 0; mi < 4; mi++)
#pragma unroll
        for (int ni = 0; ni < 4; ni++) {
            const int kg = n0 + wx * 64 + ni * 16 + ml;
#pragma unroll
            for (int r = 0; r < 4; r++) {
                const int qg = m0 + wy * 64 + mi * 16 + mq * 4 + r;
                float diff = (float)(qg - kg);
                float val = acc[mi][ni][r] * 0.0625f - diff * diff / g;
                size_t midx = ((size_t)b * S_ + qg) * S_ + kg;
                int mv;
                if (code == 0)      mv = ((const unsigned char*)mask)[midx];
                else if (code == 1) mv = ((const int*)mask)[midx];
                else if (code == 2) mv = (((const u16*)mask)[midx] != 0);
                else                mv = (((const u32*)mask)[midx] != 0);
                if (mv) val = -4294967296.0f;
                logits[((size_t)z * S_ + qg) * S_ + kg] = val;
            }
        }
}

// ---------------- row softmax in-place + query_mask scale ----------------
__global__ __launch_bounds__(256) void softmax_k(float* __restrict__ logits, const float* __restrict__ qmask) {
    const int row = blockIdx.x;                  // 32768 rows, order (h*B+b, qg)
    const int b = (row >> 10) & 7, qg = row & 1023;
    float* p = logits + (size_t)row * S_;
    const int t = threadIdx.x, wave = t >> 6;
    float4 v = ((const float4*)p)[t];
    __shared__ float red[4];
    float mx = fmaxf(fmaxf(v.x, v.y), fmaxf(v.z, v.w));
#pragma unroll
    for (int o = 32; o; o >>= 1) mx = fmaxf(mx, __shfl_xor(mx, o, 64));
    if ((t & 63) == 0) red[wave] = mx;
    __syncthreads();
    mx = fmaxf(fmaxf(red[0], red[1]), fmaxf(red[2], red[3]));
    __syncthreads();
    v.x = __expf(v.x - mx); v.y = __expf(v.y - mx);
    v.z = __expf(v.z - mx); v.w = __expf(v.w - mx);
    float s = v.x + v.y + v.z + v.w;
#pragma unroll
    for (int o = 32; o; o >>= 1) s += __shfl_xor(s, o, 64);
    if ((t & 63) == 0) red[wave] = s;
    __syncthreads();
    s = red[0] + red[1] + red[2] + red[3];
    const float sc = qmask[b * S_ + qg] / s;
    v.x *= sc; v.y *= sc; v.z *= sc; v.w *= sc;
    ((float4*)p)[t] = v;
}

// ---------------- PV: res[b*S+m][h*D + n] bf16 = attn(fp32) @ VT^T ----------------
__global__ __launch_bounds__(256) void pv_mfma_k(const float* __restrict__ attnF, const u16* __restrict__ VT,
                                                 u16* __restrict__ resB) {
    __shared__ short As[128 * 40];
    __shared__ short Bs[128 * 40];
    const int z = blockIdx.z, h = z >> 3, b = z & 7;
    const float* Ap = attnF + (size_t)z * S_ * S_;
    const u16* Bp = VT + ((size_t)(b * 1024 + h * D_)) * 1024;
    const int m0 = blockIdx.y * 128, n0 = blockIdx.x * 128;   // n0 in {0,128}
    f32x4 acc[4][4];
#pragma unroll
    for (int i = 0; i < 4; i++)
#pragma unroll
        for (int j = 0; j < 4; j++) acc[i][j] = 0;
    gemm_core<0>(Ap, nullptr, S_, Bp, 1024, S_, m0, n0, As, Bs, acc);
    u16* C = resB + (size_t)b * S_ * H_ + h * D_;
    const int lane = threadIdx.x & 63, wave = threadIdx.x >> 6;
    const int wy = wave >> 1, wx = wave & 1, mq = lane >> 4, ml = lane & 15;
#pragma unroll
    for (int mi = 0; mi < 4; mi++)
#pragma unroll
        for (int ni = 0; ni < 4; ni++) {
            const int n = n0 + wx * 64 + ni * 16 + ml;
#pragma unroll
            for (int r = 0; r < 4; r++) {
                const int m = m0 + wy * 64 + mi * 16 + mq * 4 + r;
                C[(size_t)m * H_ + n] = f2bf(acc[mi][ni][r]);
            }
        }
}

// ---------------- final: tmp[m][n] bf16 = [dec|res] @ WfT^T + bf + dec ----------------
__global__ __launch_bounds__(256) void final_mfma_k(const float* __restrict__ dec, const u16* __restrict__ resB,
                                                    const u16* __restrict__ WfT, const float* __restrict__ bfv,
                                                    u16* __restrict__ tmp) {
    __shared__ short As[128 * 40];
    __shared__ short Bs[128 * 40];
    const int m0 = blockIdx.y * 128, n0 = blockIdx.x * 128;
    f32x4 acc[4][4];
#pragma unroll
    for (int i = 0; i < 4; i++)
#pragma unroll
        for (int j = 0; j < 4; j++) acc[i][j] = 0;
    gemm_core<2>(dec, resB, H_, WfT, 2048, 2048, m0, n0, As, Bs, acc);
    const int lane = threadIdx.x & 63, wave = threadIdx.x >> 6;
    const int wy = wave >> 1, wx = wave & 1, mq = lane >> 4, ml = lane & 15;
#pragma unroll
    for (int mi = 0; mi < 4; mi++)
#pragma unroll
        for (int ni = 0; ni < 4; ni++) {
            const int n = n0 + wx * 64 + ni * 16 + ml;
#pragma unroll
            for (int r = 0; r < 4; r++) {
                const int m = m0 + wy * 64 + mi * 16 + mq * 4 + r;
                float val = acc[mi][ni][r] + bfv[n] + dec[(size_t)m * H_ + n];
                tmp[(size_t)m * H_ + n] = f2bf(val);
            }
        }
}

// ---------------- LayerNorm (bf16 tmp -> fp32 out) ----------------
__global__ __launch_bounds__(256) void ln2_k(const u16* __restrict__ tmp, const float* __restrict__ gm,
                                             const float* __restrict__ bt, float* __restrict__ out) {
    const int m = blockIdx.x, t = threadIdx.x;
    ushort4 u = ((const ushort4*)(tmp + (size_t)m * H_))[t];
    float xa[4] = {bf2f(u.x), bf2f(u.y), bf2f(u.z), bf2f(u.w)};
    float s = 0.f, s2 = 0.f;
#pragma unroll
    for (int i = 0; i < 4; i++) { s += xa[i]; s2 += xa[i] * xa[i]; }
#pragma unroll
    for (int o = 32; o; o >>= 1) { s += __shfl_xor(s, o, 64); s2 += __shfl_xor(s2, o, 64); }
    __shared__ float rs[4], rs2[4];
    if ((t & 63) == 0) { rs[t >> 6] = s; rs2[t >> 6] = s2; }
    __syncthreads();
    s  = rs[0] + rs[1] + rs[2] + rs[3];
    s2 = rs2[0] + rs2[1] + rs2[2] + rs2[3];
    float mu = s * (1.f / 1024.f);
    float var = s2 * (1.f / 1024.f) - mu * mu;
    float rstd = rsqrtf(var + 1e-5f);
    float ov[4];
#pragma unroll
    for (int i = 0; i < 4; i++) {
        int n = t * 4 + i;
        ov[i] = (xa[i] - mu) * rstd * gm[n] + bt[n];
    }
    *(float4*)(out + (size_t)m * H_ + t * 4) = make_float4(ov[0], ov[1], ov[2], ov[3]);
}

extern "C" void kernel_launch(void* const* d_in, const int* in_sizes, int n_in,
                              void* d_out, int out_size, void* d_ws, size_t ws_size,
                              hipStream_t stream) {
    const float* memory = (const float*)d_in[0];
    const float* dec    = (const float*)d_in[1];
    const void*  mask   = d_in[2];
    const float* qmask  = (const float*)d_in[3];
    const float* Wk     = (const float*)d_in[4];
    const float* Wv     = (const float*)d_in[5];
    const float* Wq     = (const float*)d_in[6];
    const float* Wf     = (const float*)d_in[7];
    const float* bfv    = (const float*)d_in[8];
    const float* gamma  = (const float*)d_in[9];
    const float* beta   = (const float*)d_in[10];
    const float* gfac   = (const float*)d_in[11];

    // ---- workspace layout (peak 59 MiB) ----
    // [0,1M) flags | [1,3) WqT | [3,5) WkT | [5,7) WvT | [7,11) WfT
    // [11,27) Qb bf16  (tmp bf16 aliases after QK)
    // [27,43) Kb bf16  (resB aliases after softmax)
    // [43,59) VT bf16
    char* ws = (char*)d_ws;
    int* fl  = (int*)ws;
    u16* WqT = (u16*)(ws + (1u  << 20));
    u16* WkT = (u16*)(ws + (3u  << 20));
    u16* WvT = (u16*)(ws + (5u  << 20));
    u16* WfT = (u16*)(ws + (7u  << 20));
    u16* Qb  = (u16*)(ws + (11u << 20));
    u16* Kb  = (u16*)(ws + (27u << 20));
    u16* VT  = (u16*)(ws + (43u << 20));
    u16* resB = Kb;          // Kb dead after qk_logits_k
    u16* tmpB = Qb;          // Qb dead after qk_logits_k

    float* out   = (float*)d_out;
    float* attnF = out + (size_t)B_ * S_ * H_;   // logits -> softmax in-place -> final attn

    init_flags_k<<<1, 1, 0, stream>>>(fl);
    or_mask_k<<<256, 256, 0, stream>>>((const u32*)mask, fl);
    classify_mask_k<<<1, 1, 0, stream>>>(fl);

    tcast_k<<<dim3(32, 32), 256, 0, stream>>>(Wq, WqT, 1024, 1024);
    tcast_k<<<dim3(32, 32), 256, 0, stream>>>(Wk, WkT, 1024, 1024);
    tcast_k<<<dim3(32, 32), 256, 0, stream>>>(Wv, WvT, 1024, 1024);
    tcast_k<<<dim3(32, 64), 256, 0, stream>>>(Wf, WfT, 2048, 1024);

    gemm_proj_k<<<dim3(8, 64), 256, 0, stream>>>(dec,    WqT, Qb);
    gemm_proj_k<<<dim3(8, 64), 256, 0, stream>>>(memory, WkT, Kb);
    gemm_vt_k  <<<dim3(8, 64), 256, 0, stream>>>(memory, WvT, VT);

    qk_logits_k<<<dim3(8, 8, 32), 256, 0, stream>>>(Qb, Kb, mask, gfac, fl, attnF);
    softmax_k<<<32768, 256, 0, stream>>>(attnF, qmask);
    pv_mfma_k<<<dim3(2, 8, 32), 256, 0, stream>>>(attnF, VT, resB);
    final_mfma_k<<<dim3(8, 64), 256, 0, stream>>>(dec, resB, WfT, bfv, tmpB);
    ln2_k<<<M_, 256, 0, stream>>>(tmpB, gamma, beta, out);
}